// Round 16
// baseline (105.589 us; speedup 1.0000x reference)
//
#include <hip/hip_runtime.h>
#include <hip/hip_bf16.h>

#define N 8192
#define D 128
#define NG 64                // 128-row groups
#define NTILE 2080           // NG*(NG+1)/2 upper-triangle tiles
#define NLBL 100             // labels in [0,100)
#define LCHK 8               // labelsum chunks (1024 rows each)
#define NLTASK (NLBL * LCHK) // 800 labelsum tasks
#define NTASK (NTILE + NLTASK)

#define K1F 14.426950408889634f    // 10 * log2(e)
#define K0F (-14.426950408889634f)

#if __has_builtin(__builtin_amdgcn_exp2f)
#define EXP2(x) __builtin_amdgcn_exp2f(x)
#else
#define EXP2(x) exp2f(x)
#endif

typedef __attribute__((ext_vector_type(8))) short bf16x8;
typedef __attribute__((ext_vector_type(4))) float f32x4;
typedef __attribute__((address_space(1))) const unsigned int gu32;
typedef __attribute__((address_space(3))) unsigned int lu32;

// ---------------- K1: row-normalize z -> bf16 zn, self-dot d_ii, histogram --
__global__ __launch_bounds__(256) void znorm_kernel(const float* __restrict__ z,
                                                    const int* __restrict__ y,
                                                    ushort* __restrict__ zn,
                                                    float* __restrict__ dii,
                                                    int* __restrict__ cntI) {
    const int wid  = threadIdx.x >> 6;
    const int lane = threadIdx.x & 63;
    const int row  = blockIdx.x * 4 + wid;       // grid = N/4 blocks
    const float2 v = reinterpret_cast<const float2*>(z + (size_t)row * D)[lane];
    float ss = v.x * v.x + v.y * v.y;
    #pragma unroll
    for (int m = 1; m < 64; m <<= 1) ss += __shfl_xor(ss, m);
    const float inv = 1.0f / fmaxf(sqrtf(ss), 1e-8f);
    __hip_bfloat16 b0 = __float2bfloat16(v.x * inv);
    __hip_bfloat16 b1 = __float2bfloat16(v.y * inv);
    ushort2 o;
    o.x = *reinterpret_cast<ushort*>(&b0);
    o.y = *reinterpret_cast<ushort*>(&b1);
    reinterpret_cast<ushort2*>(zn + (size_t)row * D)[lane] = o;
    const float f0 = __bfloat162float(b0), f1 = __bfloat162float(b1);
    float s2 = f0 * f0 + f1 * f1;
    #pragma unroll
    for (int m = 1; m < 64; m <<= 1) s2 += __shfl_xor(s2, m);
    if (lane == 0) dii[row] = s2;
    // label histogram: int atomics -> order-independent, deterministic
    if (threadIdx.x < 4) atomicAdd(&cntI[y[blockIdx.x * 4 + threadIdx.x]], 1);
}

// ---------------- K2: unified task kernel -----------------------------------
// Tasks 0..799: labelsum (label c, 1024-row chunk k) -> tpart[k][c][:]
// Tasks 800..2879: upper-triangle 128x128 exp-sum tiles (R15 body verbatim).
// Label tasks and tile tasks are independent (both read only zn/y) -> they
// co-execute in ONE dispatch; label scans soak into the tile waves' stall
// slots instead of serializing as a separate kernel.
union SmemU {
    struct { ushort B[128 * D]; float zc[4][128]; } m;  // 34.8 KB (tile task)
    int ly[1024];                                       // 4 KB (label task)
};

__global__ __launch_bounds__(256, 4) void supcon_main(const ushort* __restrict__ zn,
                                                      const int* __restrict__ y,
                                                      float* __restrict__ P,
                                                      float* __restrict__ tpart) {
    __shared__ SmemU sm;
    const int task = blockIdx.x;

    if (task < NLTASK) {
        // ---- labelsum task: label c over rows [k*1024, (k+1)*1024)
        const int c = task >> 3;
        const int k = task & 7;
        for (int j = threadIdx.x; j < 1024; j += 256)
            sm.ly[j] = y[k * 1024 + j];
        __syncthreads();
        if (threadIdx.x < D) {
            const int d = threadIdx.x;
            float acc = 0.0f;
            for (int j = 0; j < 1024; ++j) {
                if (sm.ly[j] == c) {              // block-uniform -> branch skip
                    __hip_bfloat16 hb;
                    *reinterpret_cast<ushort*>(&hb) = zn[(size_t)(k * 1024 + j) * D + d];
                    acc += __bfloat162float(hb);
                }
            }
            tpart[((size_t)k * NLBL + c) * D + d] = acc;
        }
        return;
    }

    // ---- tile task (R15 verified body)
    const int t = task - NLTASK;
    const int wid  = threadIdx.x >> 6;
    const int lane = threadIdx.x & 63;
    const int g    = lane >> 4;
    const int lj   = lane & 15;

    // decode tile index -> (r, c): t = r*(129-r)/2 + (c-r)
    int r = (int)((129.0f - sqrtf(16641.0f - 8.0f * (float)t)) * 0.5f);
    r = r < 0 ? 0 : (r > 63 ? 63 : r);
    while (r > 0 && (r * (129 - r)) / 2 > t) --r;
    while (((r + 1) * (129 - (r + 2))) / 2 + (r + 1) <= t) ++r;
    const int c = r + (t - (r * (129 - r)) / 2);

    const int rowBase = r * 128 + wid * 32;
    const size_t colBase = (size_t)c * 128;

    // stage B tile (128x128, 32 KB): linear LDS dest, pre-swizzled source
    const int lrow4 = lane >> 4;
    const int sslot = lane & 15;
    #pragma unroll
    for (int c2 = 0; c2 < 8; ++c2) {
        const int row = wid * 32 + c2 * 4 + lrow4;
        const ushort* src = zn + (colBase + row) * D + ((sslot ^ (row & 7)) * 8);
        __builtin_amdgcn_global_load_lds((gu32*)src,
                                         (lu32*)&sm.m.B[(wid * 8 + c2) * 512], 16, 0, 0);
    }

    bf16x8 a[2][4];
    #pragma unroll
    for (int m = 0; m < 2; ++m) {
        const ushort* rp = zn + (size_t)(rowBase + m * 16 + lj) * D;
        #pragma unroll
        for (int s = 0; s < 4; ++s)
            a[m][s] = *reinterpret_cast<const bf16x8*>(rp + s * 32 + g * 8);
    }

    float Zrow[2][4];
    #pragma unroll
    for (int m = 0; m < 2; ++m)
        #pragma unroll
        for (int rr = 0; rr < 4; ++rr) Zrow[m][rr] = 0.0f;
    float zcol[8];

    asm volatile("s_waitcnt vmcnt(0)");
    __syncthreads();

    const f32x4 zero4 = {0.f, 0.f, 0.f, 0.f};
    #pragma unroll
    for (int jt = 0; jt < 8; ++jt) {
        const int brow = jt * 16 + lj;
        const int rx   = brow & 7;
        bf16x8 b[4];
        #pragma unroll
        for (int s = 0; s < 4; ++s)
            b[s] = *reinterpret_cast<const bf16x8*>(
                &sm.m.B[brow * D + (((s * 4 + g) ^ rx) * 8)]);
        f32x4 acc[2] = {zero4, zero4};
        #pragma unroll
        for (int s = 0; s < 4; ++s)
            #pragma unroll
            for (int m = 0; m < 2; ++m)
                acc[m] = __builtin_amdgcn_mfma_f32_16x16x32_bf16(a[m][s], b[s], acc[m], 0, 0, 0);
        float esum = 0.0f;
        #pragma unroll
        for (int m = 0; m < 2; ++m)
            #pragma unroll
            for (int rr = 0; rr < 4; ++rr) {
                const float e = EXP2(fmaf(acc[m][rr], K1F, K0F));  // exp(10*dot-10)
                Zrow[m][rr] += e;
                esum += e;
            }
        zcol[jt] = esum;
    }

    // row side -> P[c][rows of r]
    #pragma unroll
    for (int m = 0; m < 2; ++m)
        #pragma unroll
        for (int rr = 0; rr < 4; ++rr)
            #pragma unroll
            for (int mk = 1; mk < 16; mk <<= 1)
                Zrow[m][rr] += __shfl_xor(Zrow[m][rr], mk);
    if (lj == 0) {
        #pragma unroll
        for (int m = 0; m < 2; ++m)
            #pragma unroll
            for (int rr = 0; rr < 4; ++rr)
                P[(size_t)c * N + rowBase + m * 16 + g * 4 + rr] = Zrow[m][rr];
    }

    // col side (off-diagonal) -> P[r][cols of c]
    if (r != c) {
        #pragma unroll
        for (int jt = 0; jt < 8; ++jt) {
            zcol[jt] += __shfl_xor(zcol[jt], 16);
            zcol[jt] += __shfl_xor(zcol[jt], 32);
        }
        if (lane < 16) {
            #pragma unroll
            for (int jt = 0; jt < 8; ++jt)
                sm.m.zc[wid][jt * 16 + lane] = zcol[jt];
        }
        __syncthreads();
        if (threadIdx.x < 128) {
            const float s = sm.m.zc[0][threadIdx.x] + sm.m.zc[1][threadIdx.x] +
                            sm.m.zc[2][threadIdx.x] + sm.m.zc[3][threadIdx.x];
            P[(size_t)r * N + colBase + threadIdx.x] = s;
        }
    }
}

// ---------------- K3: finalize (t-reduction folded in) ----------------------
__global__ __launch_bounds__(256) void supcon_finalize(const ushort* __restrict__ zn,
                                                       const int* __restrict__ y,
                                                       const float* __restrict__ P,
                                                       const float* __restrict__ dii,
                                                       const float* __restrict__ tpart,
                                                       const int* __restrict__ cntI,
                                                       float* __restrict__ out) {
    const int wid  = threadIdx.x >> 6;
    const int lane = threadIdx.x & 63;
    const int row  = blockIdx.x * 4 + wid;
    const int c    = y[row];
    const ushort2 u = reinterpret_cast<const ushort2*>(zn + (size_t)row * D)[lane];
    // on-the-fly t[c] = sum_k tpart[k][c][:]; lane owns dims 2*lane, 2*lane+1
    float tvx = 0.0f, tvy = 0.0f;
    #pragma unroll
    for (int k = 0; k < LCHK; ++k) {
        const float2 tp = *reinterpret_cast<const float2*>(
            &tpart[((size_t)k * NLBL + c) * D + 2 * lane]);
        tvx += tp.x;
        tvy += tp.y;
    }
    __hip_bfloat16 h0, h1;
    *reinterpret_cast<ushort*>(&h0) = u.x;
    *reinterpret_cast<ushort*>(&h1) = u.y;
    float dot = __bfloat162float(h0) * tvx + __bfloat162float(h1) * tvy;
    #pragma unroll
    for (int m = 1; m < 64; m <<= 1) dot += __shfl_xor(dot, m);
    // 64 Z-partials, one per lane
    float zs = P[(size_t)lane * N + row];
    #pragma unroll
    for (int m = 1; m < 64; m <<= 1) zs += __shfl_xor(zs, m);
    if (lane == 0) {
        const float di = dii[row];
        const float zc = zs - EXP2(fmaf(di, K1F, K0F));   // remove self term
        const float cn = (float)cntI[c] - 1.0f;           // exclude self
        const float S  = dot - di;                        // exclude self
        const float denom = fmaxf(cn, 1.0f);
        const float lse   = 10.0f + logf(zc);
        out[row] = -(10.0f * S) / denom + (cn > 0.5f ? lse : 0.0f);
    }
}

extern "C" void kernel_launch(void* const* d_in, const int* in_sizes, int n_in,
                              void* d_out, int out_size, void* d_ws, size_t ws_size,
                              hipStream_t stream) {
    const float* z = (const float*)d_in[0];
    const int*   y = (const int*)d_in[1];
    float* out = (float*)d_out;

    // ws layout (~4.7 MB)
    ushort* zn    = (ushort*)d_ws;                                  // 2 MB
    float*  dii   = (float*)((char*)d_ws + (size_t)N * D * 2);      // 32 KB
    float*  tpart = dii + N;                                        // 409.6 KB
    int*    cntI  = (int*)(tpart + (size_t)LCHK * NLBL * D);        // 400 B (pad 512)
    float*  P     = (float*)((char*)cntI + 512);                    // 2 MB (64 x N)

    hipMemsetAsync(cntI, 0, NLBL * sizeof(int), stream);
    znorm_kernel<<<N / 4, 256, 0, stream>>>(z, y, zn, dii, cntI);
    supcon_main<<<NTASK, 256, 0, stream>>>(zn, y, P, tpart);
    supcon_finalize<<<N / 4, 256, 0, stream>>>(zn, y, P, dii, tpart, cntI, out);
}

// Round 17
// 65.124 us; speedup vs baseline: 1.6213x; 1.6213x over previous
//
#include <hip/hip_runtime.h>
#include <hip/hip_bf16.h>

#define N 8192
#define D 128
#define NG 64                // 128-row groups
#define NTILE 2080           // NG*(NG+1)/2 upper-triangle tiles
#define NLBL 100             // labels in [0,100)
#define LCHK 8               // labelsum chunks (1024 rows each)

#define K1F 14.426950408889634f    // 10 * log2(e)
#define K0F (-14.426950408889634f)

#if __has_builtin(__builtin_amdgcn_exp2f)
#define EXP2(x) __builtin_amdgcn_exp2f(x)
#else
#define EXP2(x) exp2f(x)
#endif

typedef __attribute__((ext_vector_type(8))) short bf16x8;
typedef __attribute__((ext_vector_type(4))) float f32x4;
typedef __attribute__((address_space(1))) const unsigned int gu32;
typedef __attribute__((address_space(3))) unsigned int lu32;

// ---------------- K1: row-normalize z -> bf16 zn, self-dot d_ii, histogram --
__global__ __launch_bounds__(256) void znorm_kernel(const float* __restrict__ z,
                                                    const int* __restrict__ y,
                                                    ushort* __restrict__ zn,
                                                    float* __restrict__ dii,
                                                    int* __restrict__ cntI) {
    const int wid  = threadIdx.x >> 6;
    const int lane = threadIdx.x & 63;
    const int row  = blockIdx.x * 4 + wid;       // grid = N/4 blocks
    const float2 v = reinterpret_cast<const float2*>(z + (size_t)row * D)[lane];
    float ss = v.x * v.x + v.y * v.y;
    #pragma unroll
    for (int m = 1; m < 64; m <<= 1) ss += __shfl_xor(ss, m);
    const float inv = 1.0f / fmaxf(sqrtf(ss), 1e-8f);
    __hip_bfloat16 b0 = __float2bfloat16(v.x * inv);
    __hip_bfloat16 b1 = __float2bfloat16(v.y * inv);
    ushort2 o;
    o.x = *reinterpret_cast<ushort*>(&b0);
    o.y = *reinterpret_cast<ushort*>(&b1);
    reinterpret_cast<ushort2*>(zn + (size_t)row * D)[lane] = o;
    const float f0 = __bfloat162float(b0), f1 = __bfloat162float(b1);
    float s2 = f0 * f0 + f1 * f1;
    #pragma unroll
    for (int m = 1; m < 64; m <<= 1) s2 += __shfl_xor(s2, m);
    if (lane == 0) dii[row] = s2;
    // label histogram: int atomics -> order-independent, deterministic
    if (threadIdx.x < 4) atomicAdd(&cntI[y[blockIdx.x * 4 + threadIdx.x]], 1);
}

// ---------------- K2: labelsum via deterministic match-compaction ------------
// Block (c,k): rows [k*1024,(k+1)*1024), label c. Phase 1: each thread scans
// 4 rows from GLOBAL y (coalesced, no serial LDS chain), Hillis-Steele prefix
// in LDS -> ordered (ascending) index list. Phase 2: ~10 independent row
// loads accumulated in fixed order by 128 dim-threads. Deterministic.
__global__ __launch_bounds__(256) void labelsum_kernel(const ushort* __restrict__ zn,
                                                       const int* __restrict__ y,
                                                       float* __restrict__ tpart) {
    __shared__ int idxs[1024];
    __shared__ int sc[256];
    const int c = blockIdx.x / LCHK;
    const int k = blockIdx.x % LCHK;
    const int t = threadIdx.x;
    const int base = k * 1024;

    int ys0 = y[base + t * 4 + 0], ys1 = y[base + t * 4 + 1];
    int ys2 = y[base + t * 4 + 2], ys3 = y[base + t * 4 + 3];
    const int m0 = (ys0 == c), m1 = (ys1 == c), m2 = (ys2 == c), m3 = (ys3 == c);
    const int myCnt = m0 + m1 + m2 + m3;
    sc[t] = myCnt;
    __syncthreads();
    #pragma unroll
    for (int off = 1; off < 256; off <<= 1) {
        const int v = sc[t];
        const int add = (t >= off) ? sc[t - off] : 0;
        __syncthreads();
        sc[t] = v + add;
        __syncthreads();
    }
    const int total = sc[255];
    int pos = sc[t] - myCnt;                      // exclusive prefix
    if (m0) idxs[pos++] = t * 4 + 0;
    if (m1) idxs[pos++] = t * 4 + 1;
    if (m2) idxs[pos++] = t * 4 + 2;
    if (m3) idxs[pos++] = t * 4 + 3;
    __syncthreads();

    if (t < D) {
        float acc = 0.0f;
        int i = 0;
        for (; i + 4 <= total; i += 4) {          // batch 4: independent loads
            const int r0 = idxs[i], r1 = idxs[i + 1], r2 = idxs[i + 2], r3 = idxs[i + 3];
            __hip_bfloat16 h0, h1, h2, h3;
            *reinterpret_cast<ushort*>(&h0) = zn[(size_t)(base + r0) * D + t];
            *reinterpret_cast<ushort*>(&h1) = zn[(size_t)(base + r1) * D + t];
            *reinterpret_cast<ushort*>(&h2) = zn[(size_t)(base + r2) * D + t];
            *reinterpret_cast<ushort*>(&h3) = zn[(size_t)(base + r3) * D + t];
            acc += __bfloat162float(h0);
            acc += __bfloat162float(h1);
            acc += __bfloat162float(h2);
            acc += __bfloat162float(h3);
        }
        for (; i < total; ++i) {
            __hip_bfloat16 hb;
            *reinterpret_cast<ushort*>(&hb) = zn[(size_t)(base + idxs[i]) * D + t];
            acc += __bfloat162float(hb);
        }
        tpart[((size_t)k * NLBL + c) * D + t] = acc;
    }
}

// ---------------- K3: upper-triangle tiles, FRAGMENT-ORDER LDS ---------------
// sim symmetric -> 2080 tiles (r<=c). B staged into LDS in FRAGMENT order:
// entry [(jt*4+s)*64 + lane] holds the exact 16B lane consumes in MFMA(jt,s).
// global_load_lds writes lane -> base+lane*16 (linear), so the fragment
// permutation is encoded in the per-lane SOURCE address (free). Compute
// ds_reads are lane-linear -> ZERO bank conflicts (R16 measured 6.39M with
// the row-XOR layout), and no address math in the inner loop.
__global__ __launch_bounds__(256, 4) void supcon_main(const ushort* __restrict__ zn,
                                                      float* __restrict__ P) {
    __shared__ ushort Bsm[32 * 64 * 8];   // 32 KB: [jt*4+s][lane] 16B entries
    __shared__ float  zcLDS[4][128];      // 2 KB
    const int wid  = threadIdx.x >> 6;
    const int lane = threadIdx.x & 63;
    const int g    = lane >> 4;
    const int lj   = lane & 15;

    // decode tile index -> (r, c): t = r*(129-r)/2 + (c-r)
    const int t = blockIdx.x;
    int r = (int)((129.0f - sqrtf(16641.0f - 8.0f * (float)t)) * 0.5f);
    r = r < 0 ? 0 : (r > 63 ? 63 : r);
    while (r > 0 && (r * (129 - r)) / 2 > t) --r;
    while (((r + 1) * (129 - (r + 2))) / 2 + (r + 1) <= t) ++r;
    const int c = r + (t - (r * (129 - r)) / 2);

    const int rowBase = r * 128 + wid * 32;
    const size_t colBase = (size_t)c * 128;

    // stage: wave w covers jt in {2w, 2w+1}, s in 0..3 (8 calls x 1 KB).
    // lane L sources row jt*16+(L&15), dims s*32+(L>>4)*8 .. +8
    #pragma unroll
    for (int q = 0; q < 8; ++q) {
        const int jt = wid * 2 + (q >> 2);
        const int s  = q & 3;
        const ushort* src = zn + (colBase + jt * 16 + lj) * D + s * 32 + g * 8;
        __builtin_amdgcn_global_load_lds((gu32*)src,
                                         (lu32*)&Bsm[(jt * 4 + s) * 64 * 8], 16, 0, 0);
    }

    // A fragments: 2 M-tiles x 4 K-steps (32 VGPR)
    bf16x8 a[2][4];
    #pragma unroll
    for (int m = 0; m < 2; ++m) {
        const ushort* rp = zn + (size_t)(rowBase + m * 16 + lj) * D;
        #pragma unroll
        for (int s = 0; s < 4; ++s)
            a[m][s] = *reinterpret_cast<const bf16x8*>(rp + s * 32 + g * 8);
    }

    float Zrow[2][4];
    #pragma unroll
    for (int m = 0; m < 2; ++m)
        #pragma unroll
        for (int rr = 0; rr < 4; ++rr) Zrow[m][rr] = 0.0f;
    float zcol[8];

    asm volatile("s_waitcnt vmcnt(0)");
    __syncthreads();

    const f32x4 zero4 = {0.f, 0.f, 0.f, 0.f};
    #pragma unroll
    for (int jt = 0; jt < 8; ++jt) {
        bf16x8 b[4];
        #pragma unroll
        for (int s = 0; s < 4; ++s)
            b[s] = *reinterpret_cast<const bf16x8*>(
                &Bsm[((jt * 4 + s) * 64 + lane) * 8]);   // lane-linear: conflict-free
        f32x4 acc[2] = {zero4, zero4};
        #pragma unroll
        for (int s = 0; s < 4; ++s)
            #pragma unroll
            for (int m = 0; m < 2; ++m)
                acc[m] = __builtin_amdgcn_mfma_f32_16x16x32_bf16(a[m][s], b[s], acc[m], 0, 0, 0);
        float esum = 0.0f;
        #pragma unroll
        for (int m = 0; m < 2; ++m)
            #pragma unroll
            for (int rr = 0; rr < 4; ++rr) {
                const float e = EXP2(fmaf(acc[m][rr], K1F, K0F));  // exp(10*dot-10)
                Zrow[m][rr] += e;
                esum += e;
            }
        zcol[jt] = esum;
    }

    // row side -> P[c][rows of r]
    #pragma unroll
    for (int m = 0; m < 2; ++m)
        #pragma unroll
        for (int rr = 0; rr < 4; ++rr)
            #pragma unroll
            for (int mk = 1; mk < 16; mk <<= 1)
                Zrow[m][rr] += __shfl_xor(Zrow[m][rr], mk);
    if (lj == 0) {
        #pragma unroll
        for (int m = 0; m < 2; ++m)
            #pragma unroll
            for (int rr = 0; rr < 4; ++rr)
                P[(size_t)c * N + rowBase + m * 16 + g * 4 + rr] = Zrow[m][rr];
    }

    // col side (off-diagonal) -> P[r][cols of c]
    if (r != c) {
        #pragma unroll
        for (int jt = 0; jt < 8; ++jt) {
            zcol[jt] += __shfl_xor(zcol[jt], 16);
            zcol[jt] += __shfl_xor(zcol[jt], 32);
        }
        if (lane < 16) {
            #pragma unroll
            for (int jt = 0; jt < 8; ++jt)
                zcLDS[wid][jt * 16 + lane] = zcol[jt];
        }
        __syncthreads();
        if (threadIdx.x < 128) {
            const float s = zcLDS[0][threadIdx.x] + zcLDS[1][threadIdx.x] +
                            zcLDS[2][threadIdx.x] + zcLDS[3][threadIdx.x];
            P[(size_t)r * N + colBase + threadIdx.x] = s;
        }
    }
}

// ---------------- K4: finalize (t-reduction folded in) ----------------------
__global__ __launch_bounds__(256) void supcon_finalize(const ushort* __restrict__ zn,
                                                       const int* __restrict__ y,
                                                       const float* __restrict__ P,
                                                       const float* __restrict__ dii,
                                                       const float* __restrict__ tpart,
                                                       const int* __restrict__ cntI,
                                                       float* __restrict__ out) {
    const int wid  = threadIdx.x >> 6;
    const int lane = threadIdx.x & 63;
    const int row  = blockIdx.x * 4 + wid;
    const int c    = y[row];
    const ushort2 u = reinterpret_cast<const ushort2*>(zn + (size_t)row * D)[lane];
    // on-the-fly t[c] = sum_k tpart[k][c][:]; lane owns dims 2*lane, 2*lane+1
    float tvx = 0.0f, tvy = 0.0f;
    #pragma unroll
    for (int k = 0; k < LCHK; ++k) {
        const float2 tp = *reinterpret_cast<const float2*>(
            &tpart[((size_t)k * NLBL + c) * D + 2 * lane]);
        tvx += tp.x;
        tvy += tp.y;
    }
    __hip_bfloat16 h0, h1;
    *reinterpret_cast<ushort*>(&h0) = u.x;
    *reinterpret_cast<ushort*>(&h1) = u.y;
    float dot = __bfloat162float(h0) * tvx + __bfloat162float(h1) * tvy;
    #pragma unroll
    for (int m = 1; m < 64; m <<= 1) dot += __shfl_xor(dot, m);
    // 64 Z-partials, one per lane
    float zs = P[(size_t)lane * N + row];
    #pragma unroll
    for (int m = 1; m < 64; m <<= 1) zs += __shfl_xor(zs, m);
    if (lane == 0) {
        const float di = dii[row];
        const float zc = zs - EXP2(fmaf(di, K1F, K0F));   // remove self term
        const float cn = (float)cntI[c] - 1.0f;           // exclude self
        const float S  = dot - di;                        // exclude self
        const float denom = fmaxf(cn, 1.0f);
        const float lse   = 10.0f + logf(zc);
        out[row] = -(10.0f * S) / denom + (cn > 0.5f ? lse : 0.0f);
    }
}

extern "C" void kernel_launch(void* const* d_in, const int* in_sizes, int n_in,
                              void* d_out, int out_size, void* d_ws, size_t ws_size,
                              hipStream_t stream) {
    const float* z = (const float*)d_in[0];
    const int*   y = (const int*)d_in[1];
    float* out = (float*)d_out;

    // ws layout (~4.7 MB)
    ushort* zn    = (ushort*)d_ws;                                  // 2 MB
    float*  dii   = (float*)((char*)d_ws + (size_t)N * D * 2);      // 32 KB
    float*  tpart = dii + N;                                        // 409.6 KB
    int*    cntI  = (int*)(tpart + (size_t)LCHK * NLBL * D);        // 400 B (pad 512)
    float*  P     = (float*)((char*)cntI + 512);                    // 2 MB (64 x N)

    hipMemsetAsync(cntI, 0, NLBL * sizeof(int), stream);
    znorm_kernel<<<N / 4, 256, 0, stream>>>(z, y, zn, dii, cntI);
    labelsum_kernel<<<NLBL * LCHK, 256, 0, stream>>>(zn, y, tpart);
    supcon_main<<<NTILE, 256, 0, stream>>>(zn, P);
    supcon_finalize<<<N / 4, 256, 0, stream>>>(zn, y, P, dii, tpart, cntI, out);
}

// Round 18
// 43.324 us; speedup vs baseline: 2.4372x; 1.5032x over previous
//
#include <hip/hip_runtime.h>
#include <hip/hip_bf16.h>

#define N 8192
#define D 128
#define NG 64                // 128-row groups
#define NTILE 2080           // NG*(NG+1)/2 upper-triangle tiles
#define NLBL 100             // labels in [0,100)
#define LCHK 8               // labelsum chunks (1024 rows each)

#define K1F 14.426950408889634f    // 10 * log2(e)
#define K0F (-14.426950408889634f)

#if __has_builtin(__builtin_amdgcn_exp2f)
#define EXP2(x) __builtin_amdgcn_exp2f(x)
#else
#define EXP2(x) exp2f(x)
#endif

typedef __attribute__((ext_vector_type(8))) short bf16x8;
typedef __attribute__((ext_vector_type(4))) float f32x4;
typedef __attribute__((address_space(1))) const unsigned int gu32;
typedef __attribute__((address_space(3))) unsigned int lu32;

// ---------------- K1: row-normalize z -> bf16 zn, plus self-dot d_ii --------
__global__ __launch_bounds__(256) void znorm_kernel(const float* __restrict__ z,
                                                    ushort* __restrict__ zn,
                                                    float* __restrict__ dii) {
    const int wid  = threadIdx.x >> 6;
    const int lane = threadIdx.x & 63;
    const int row  = blockIdx.x * 4 + wid;       // grid = N/4 blocks
    const float2 v = reinterpret_cast<const float2*>(z + (size_t)row * D)[lane];
    float ss = v.x * v.x + v.y * v.y;
    #pragma unroll
    for (int m = 1; m < 64; m <<= 1) ss += __shfl_xor(ss, m);
    const float inv = 1.0f / fmaxf(sqrtf(ss), 1e-8f);
    __hip_bfloat16 b0 = __float2bfloat16(v.x * inv);
    __hip_bfloat16 b1 = __float2bfloat16(v.y * inv);
    ushort2 o;
    o.x = *reinterpret_cast<ushort*>(&b0);
    o.y = *reinterpret_cast<ushort*>(&b1);
    reinterpret_cast<ushort2*>(zn + (size_t)row * D)[lane] = o;
    const float f0 = __bfloat162float(b0), f1 = __bfloat162float(b1);
    float s2 = f0 * f0 + f1 * f1;
    #pragma unroll
    for (int m = 1; m < 64; m <<= 1) s2 += __shfl_xor(s2, m);
    if (lane == 0) dii[row] = s2;
}

// ---------------- K2: labelsum via deterministic match-compaction ------------
// Block (c,k): rows [k*1024,(k+1)*1024), label c. Phase 1: each thread scans
// 4 rows from GLOBAL y (coalesced), Hillis-Steele prefix in LDS -> ordered
// index list; ALSO writes the exact count to cpart (replaces the atomic
// histogram + 41-us hipMemsetAsync that serialized R17). Phase 2: ~10
// independent row loads accumulated in fixed order. Deterministic.
__global__ __launch_bounds__(256) void labelsum_kernel(const ushort* __restrict__ zn,
                                                       const int* __restrict__ y,
                                                       float* __restrict__ tpart,
                                                       int* __restrict__ cpart) {
    __shared__ int idxs[1024];
    __shared__ int sc[256];
    const int c = blockIdx.x / LCHK;
    const int k = blockIdx.x % LCHK;
    const int t = threadIdx.x;
    const int base = k * 1024;

    int ys0 = y[base + t * 4 + 0], ys1 = y[base + t * 4 + 1];
    int ys2 = y[base + t * 4 + 2], ys3 = y[base + t * 4 + 3];
    const int m0 = (ys0 == c), m1 = (ys1 == c), m2 = (ys2 == c), m3 = (ys3 == c);
    const int myCnt = m0 + m1 + m2 + m3;
    sc[t] = myCnt;
    __syncthreads();
    #pragma unroll
    for (int off = 1; off < 256; off <<= 1) {
        const int v = sc[t];
        const int add = (t >= off) ? sc[t - off] : 0;
        __syncthreads();
        sc[t] = v + add;
        __syncthreads();
    }
    const int total = sc[255];
    int pos = sc[t] - myCnt;                      // exclusive prefix
    if (m0) idxs[pos++] = t * 4 + 0;
    if (m1) idxs[pos++] = t * 4 + 1;
    if (m2) idxs[pos++] = t * 4 + 2;
    if (m3) idxs[pos++] = t * 4 + 3;
    __syncthreads();

    if (t == 0) cpart[k * NLBL + c] = total;      // exact count, no atomics
    if (t < D) {
        float acc = 0.0f;
        int i = 0;
        for (; i + 4 <= total; i += 4) {          // batch 4: independent loads
            const int r0 = idxs[i], r1 = idxs[i + 1], r2 = idxs[i + 2], r3 = idxs[i + 3];
            __hip_bfloat16 h0, h1, h2, h3;
            *reinterpret_cast<ushort*>(&h0) = zn[(size_t)(base + r0) * D + t];
            *reinterpret_cast<ushort*>(&h1) = zn[(size_t)(base + r1) * D + t];
            *reinterpret_cast<ushort*>(&h2) = zn[(size_t)(base + r2) * D + t];
            *reinterpret_cast<ushort*>(&h3) = zn[(size_t)(base + r3) * D + t];
            acc += __bfloat162float(h0);
            acc += __bfloat162float(h1);
            acc += __bfloat162float(h2);
            acc += __bfloat162float(h3);
        }
        for (; i < total; ++i) {
            __hip_bfloat16 hb;
            *reinterpret_cast<ushort*>(&hb) = zn[(size_t)(base + idxs[i]) * D + t];
            acc += __bfloat162float(hb);
        }
        tpart[((size_t)k * NLBL + c) * D + t] = acc;
    }
}

// ---------------- K3: upper-triangle tiles, FRAGMENT-ORDER LDS ---------------
// sim symmetric -> 2080 tiles (r<=c). B staged into LDS in FRAGMENT order:
// entry [(jt*4+s)*64 + lane] holds the exact 16B lane consumes in MFMA(jt,s).
// global_load_lds writes lane -> base+lane*16 (linear), so the fragment
// permutation is encoded in the per-lane SOURCE address (free). Compute
// ds_reads are lane-linear -> ZERO bank conflicts (R16 measured 6.39M with
// the row-XOR layout), and no address math in the inner loop.
__global__ __launch_bounds__(256, 4) void supcon_main(const ushort* __restrict__ zn,
                                                      float* __restrict__ P) {
    __shared__ ushort Bsm[32 * 64 * 8];   // 32 KB: [jt*4+s][lane] 16B entries
    __shared__ float  zcLDS[4][128];      // 2 KB
    const int wid  = threadIdx.x >> 6;
    const int lane = threadIdx.x & 63;
    const int g    = lane >> 4;
    const int lj   = lane & 15;

    // decode tile index -> (r, c): t = r*(129-r)/2 + (c-r)
    const int t = blockIdx.x;
    int r = (int)((129.0f - sqrtf(16641.0f - 8.0f * (float)t)) * 0.5f);
    r = r < 0 ? 0 : (r > 63 ? 63 : r);
    while (r > 0 && (r * (129 - r)) / 2 > t) --r;
    while (((r + 1) * (129 - (r + 2))) / 2 + (r + 1) <= t) ++r;
    const int c = r + (t - (r * (129 - r)) / 2);

    const int rowBase = r * 128 + wid * 32;
    const size_t colBase = (size_t)c * 128;

    // stage: wave w covers jt in {2w, 2w+1}, s in 0..3 (8 calls x 1 KB).
    // lane L sources row jt*16+(L&15), dims s*32+(L>>4)*8 .. +8
    #pragma unroll
    for (int q = 0; q < 8; ++q) {
        const int jt = wid * 2 + (q >> 2);
        const int s  = q & 3;
        const ushort* src = zn + (colBase + jt * 16 + lj) * D + s * 32 + g * 8;
        __builtin_amdgcn_global_load_lds((gu32*)src,
                                         (lu32*)&Bsm[(jt * 4 + s) * 64 * 8], 16, 0, 0);
    }

    // A fragments: 2 M-tiles x 4 K-steps (32 VGPR)
    bf16x8 a[2][4];
    #pragma unroll
    for (int m = 0; m < 2; ++m) {
        const ushort* rp = zn + (size_t)(rowBase + m * 16 + lj) * D;
        #pragma unroll
        for (int s = 0; s < 4; ++s)
            a[m][s] = *reinterpret_cast<const bf16x8*>(rp + s * 32 + g * 8);
    }

    float Zrow[2][4];
    #pragma unroll
    for (int m = 0; m < 2; ++m)
        #pragma unroll
        for (int rr = 0; rr < 4; ++rr) Zrow[m][rr] = 0.0f;
    float zcol[8];

    asm volatile("s_waitcnt vmcnt(0)");
    __syncthreads();

    const f32x4 zero4 = {0.f, 0.f, 0.f, 0.f};
    #pragma unroll
    for (int jt = 0; jt < 8; ++jt) {
        bf16x8 b[4];
        #pragma unroll
        for (int s = 0; s < 4; ++s)
            b[s] = *reinterpret_cast<const bf16x8*>(
                &Bsm[((jt * 4 + s) * 64 + lane) * 8]);   // lane-linear: conflict-free
        f32x4 acc[2] = {zero4, zero4};
        #pragma unroll
        for (int s = 0; s < 4; ++s)
            #pragma unroll
            for (int m = 0; m < 2; ++m)
                acc[m] = __builtin_amdgcn_mfma_f32_16x16x32_bf16(a[m][s], b[s], acc[m], 0, 0, 0);
        float esum = 0.0f;
        #pragma unroll
        for (int m = 0; m < 2; ++m)
            #pragma unroll
            for (int rr = 0; rr < 4; ++rr) {
                const float e = EXP2(fmaf(acc[m][rr], K1F, K0F));  // exp(10*dot-10)
                Zrow[m][rr] += e;
                esum += e;
            }
        zcol[jt] = esum;
    }

    // row side -> P[c][rows of r]
    #pragma unroll
    for (int m = 0; m < 2; ++m)
        #pragma unroll
        for (int rr = 0; rr < 4; ++rr)
            #pragma unroll
            for (int mk = 1; mk < 16; mk <<= 1)
                Zrow[m][rr] += __shfl_xor(Zrow[m][rr], mk);
    if (lj == 0) {
        #pragma unroll
        for (int m = 0; m < 2; ++m)
            #pragma unroll
            for (int rr = 0; rr < 4; ++rr)
                P[(size_t)c * N + rowBase + m * 16 + g * 4 + rr] = Zrow[m][rr];
    }

    // col side (off-diagonal) -> P[r][cols of c]
    if (r != c) {
        #pragma unroll
        for (int jt = 0; jt < 8; ++jt) {
            zcol[jt] += __shfl_xor(zcol[jt], 16);
            zcol[jt] += __shfl_xor(zcol[jt], 32);
        }
        if (lane < 16) {
            #pragma unroll
            for (int jt = 0; jt < 8; ++jt)
                zcLDS[wid][jt * 16 + lane] = zcol[jt];
        }
        __syncthreads();
        if (threadIdx.x < 128) {
            const float s = zcLDS[0][threadIdx.x] + zcLDS[1][threadIdx.x] +
                            zcLDS[2][threadIdx.x] + zcLDS[3][threadIdx.x];
            P[(size_t)r * N + colBase + threadIdx.x] = s;
        }
    }
}

// ---------------- K4: finalize (t- and cnt-reductions folded in) ------------
__global__ __launch_bounds__(256) void supcon_finalize(const ushort* __restrict__ zn,
                                                       const int* __restrict__ y,
                                                       const float* __restrict__ P,
                                                       const float* __restrict__ dii,
                                                       const float* __restrict__ tpart,
                                                       const int* __restrict__ cpart,
                                                       float* __restrict__ out) {
    const int wid  = threadIdx.x >> 6;
    const int lane = threadIdx.x & 63;
    const int row  = blockIdx.x * 4 + wid;
    const int c    = y[row];
    const ushort2 u = reinterpret_cast<const ushort2*>(zn + (size_t)row * D)[lane];
    // on-the-fly t[c] = sum_k tpart[k][c][:]; lane owns dims 2*lane, 2*lane+1
    float tvx = 0.0f, tvy = 0.0f;
    #pragma unroll
    for (int k = 0; k < LCHK; ++k) {
        const float2 tp = *reinterpret_cast<const float2*>(
            &tpart[((size_t)k * NLBL + c) * D + 2 * lane]);
        tvx += tp.x;
        tvy += tp.y;
    }
    __hip_bfloat16 h0, h1;
    *reinterpret_cast<ushort*>(&h0) = u.x;
    *reinterpret_cast<ushort*>(&h1) = u.y;
    float dot = __bfloat162float(h0) * tvx + __bfloat162float(h1) * tvy;
    #pragma unroll
    for (int m = 1; m < 64; m <<= 1) dot += __shfl_xor(dot, m);
    // 64 Z-partials, one per lane
    float zs = P[(size_t)lane * N + row];
    #pragma unroll
    for (int m = 1; m < 64; m <<= 1) zs += __shfl_xor(zs, m);
    // label count: lanes 0..7 load the 8 chunk counts, 3-step shuffle sum
    float cf = (lane < LCHK) ? (float)cpart[lane * NLBL + c] : 0.0f;
    cf += __shfl_xor(cf, 1);
    cf += __shfl_xor(cf, 2);
    cf += __shfl_xor(cf, 4);
    if (lane == 0) {
        const float di = dii[row];
        const float zc = zs - EXP2(fmaf(di, K1F, K0F));   // remove self term
        const float cn = cf - 1.0f;                       // exclude self
        const float S  = dot - di;                        // exclude self
        const float denom = fmaxf(cn, 1.0f);
        const float lse   = 10.0f + logf(zc);
        out[row] = -(10.0f * S) / denom + (cn > 0.5f ? lse : 0.0f);
    }
}

extern "C" void kernel_launch(void* const* d_in, const int* in_sizes, int n_in,
                              void* d_out, int out_size, void* d_ws, size_t ws_size,
                              hipStream_t stream) {
    const float* z = (const float*)d_in[0];
    const int*   y = (const int*)d_in[1];
    float* out = (float*)d_out;

    // ws layout (~4.7 MB)
    ushort* zn    = (ushort*)d_ws;                                  // 2 MB
    float*  dii   = (float*)((char*)d_ws + (size_t)N * D * 2);      // 32 KB
    float*  tpart = dii + N;                                        // 409.6 KB
    int*    cpart = (int*)(tpart + (size_t)LCHK * NLBL * D);        // 3.2 KB
    float*  P     = (float*)((char*)cpart + 4096);                  // 2 MB (64 x N)

    znorm_kernel<<<N / 4, 256, 0, stream>>>(z, zn, dii);
    labelsum_kernel<<<NLBL * LCHK, 256, 0, stream>>>(zn, y, tpart, cpart);
    supcon_main<<<NTILE, 256, 0, stream>>>(zn, P);
    supcon_finalize<<<N / 4, 256, 0, stream>>>(zn, y, P, dii, tpart, cpart, out);
}